// Round 3
// baseline (902.625 us; speedup 1.0000x reference)
//
#include <hip/hip_runtime.h>
#include <hip/hip_bf16.h>

// ---------------------------------------------------------------------------
// Pipeline (W1 pushed through the linear aggregation; round-2 counters showed
// the counting-sort fill at 71MB write-through for a 4MB payload — replaced
// with coarse bucket binning + LDS-accumulated bucket gather, no f32 global
// atomics and no fine-grained scatter writes):
//   binA1: edges (go) -> 256 coarse buckets of 256 dst rows (coalesced runs)
//   xg1  = x_goal @ W1                       [16384,64]
//   obs  = x_obs  @ W1                       [65536,64]
//   gatherB1: per bucket, LDS[256x64] += xg1[src] rows; obs += LDS
//   obs  = relu(relu(obs + b1) @ W2 + b2)    (in-place)
//   binA2: edges (ot) -> 256 coarse buckets of 32 dst rows (reuses pair buf)
//   gatherB2: per bucket, LDS[32x64] += obs[src]; acc2 = LDS
//   g    = relu((x_task + acc2) @ W3 + b3); x2 = g @ W4 + b4   [8192]
//   per-graph (32 nodes) max/mean pool -> critic MLP -> out[256]
// ---------------------------------------------------------------------------

#define BUCKET_CAP 6144   // mean 4096 edges/bucket, sigma~64 -> mean+32sigma

// out[M,64] = X[M,128] @ W[128,64]   (no bias)
__global__ __launch_bounds__(256) void gemm_k128(
    const float* __restrict__ X, const float* __restrict__ W,
    float* __restrict__ out, int M)
{
    __shared__ float Ws[128 * 64];
    __shared__ float Xs[16 * 132];       // stride 132: 4-bank skew per row
    const int tid = threadIdx.x;
    for (int i = tid; i < 128 * 64 / 4; i += 256)
        ((float4*)Ws)[i] = ((const float4*)W)[i];
    const int row0 = blockIdx.x * 16;
    for (int i = tid; i < 16 * 32; i += 256) {
        int r = i >> 5, c4 = i & 31;
        float4 v = ((const float4*)(X + (size_t)(row0 + r) * 128))[c4];
        *((float4*)(Xs + r * 132 + c4 * 4)) = v;
    }
    __syncthreads();
    const int rl = tid >> 4;
    const int cg = (tid & 15) * 4;
    float a0 = 0.f, a1 = 0.f, a2 = 0.f, a3 = 0.f;
    const float* xr = Xs + rl * 132;
    #pragma unroll 8
    for (int k = 0; k < 128; ++k) {
        float xv = xr[k];
        float4 wv = *((const float4*)(Ws + k * 64 + cg));
        a0 = fmaf(xv, wv.x, a0);
        a1 = fmaf(xv, wv.y, a1);
        a2 = fmaf(xv, wv.z, a2);
        a3 = fmaf(xv, wv.w, a3);
    }
    float4 o; o.x = a0; o.y = a1; o.z = a2; o.w = a3;
    *((float4*)(out + (size_t)(row0 + rl) * 64 + cg)) = o;
}

// ------------------- coarse binning (pass A) ------------------------------
// 256 blocks x 4096 edges each. LDS histogram over 256 buckets (dst>>BSH),
// ONE global atomic per (block,bucket) to reserve a contiguous run, then
// pair writes land in consecutive addresses (full-line coalescing in L2).
template <int BSH>
__global__ __launch_bounds__(256) void bin_edges(
    const int* __restrict__ src, const int* __restrict__ dst,
    int* __restrict__ gcur, int2* __restrict__ pairs)
{
    __shared__ int hist[256];
    __shared__ int cur[256];
    const int tid = threadIdx.x;
    hist[tid] = 0;
    __syncthreads();
    const int base = blockIdx.x * 4096;
    const int4* d4 = (const int4*)(dst + base);
    const int4* s4 = (const int4*)(src + base);
    int4 dv[4];
    #pragma unroll
    for (int k = 0; k < 4; ++k) {
        dv[k] = d4[k * 256 + tid];
        atomicAdd(&hist[dv[k].x >> BSH], 1);
        atomicAdd(&hist[dv[k].y >> BSH], 1);
        atomicAdd(&hist[dv[k].z >> BSH], 1);
        atomicAdd(&hist[dv[k].w >> BSH], 1);
    }
    __syncthreads();
    cur[tid] = atomicAdd(&gcur[tid], hist[tid]);   // reserve run
    __syncthreads();
    #pragma unroll
    for (int k = 0; k < 4; ++k) {
        int4 sv = s4[k * 256 + tid];
        int d, s, b, p;
        d = dv[k].x; s = sv.x; b = d >> BSH; p = atomicAdd(&cur[b], 1);
        if (p < BUCKET_CAP) pairs[(size_t)b * BUCKET_CAP + p] = make_int2(d, s);
        d = dv[k].y; s = sv.y; b = d >> BSH; p = atomicAdd(&cur[b], 1);
        if (p < BUCKET_CAP) pairs[(size_t)b * BUCKET_CAP + p] = make_int2(d, s);
        d = dv[k].z; s = sv.z; b = d >> BSH; p = atomicAdd(&cur[b], 1);
        if (p < BUCKET_CAP) pairs[(size_t)b * BUCKET_CAP + p] = make_int2(d, s);
        d = dv[k].w; s = sv.w; b = d >> BSH; p = atomicAdd(&cur[b], 1);
        if (p < BUCKET_CAP) pairs[(size_t)b * BUCKET_CAP + p] = make_int2(d, s);
    }
}

// ------------------- bucket gather (pass B) -------------------------------
// One 512-thread WG per bucket. LDS acc of (1<<SHIFT) rows x 64 floats.
// Each wave processes one edge with all 64 lanes (lane = column):
//   - 256B source row read is one coalesced transaction
//   - ds_add_f32 at bank lane&31 -> 2-way aliasing (free, m136)
// 4 edges in flight per wave for latency hiding (8 waves -> 32 outstanding).
template <int SHIFT, bool ADD_BASE>
__global__ __launch_bounds__(512) void gather_bucket(
    const int2* __restrict__ pairs, const int* __restrict__ cnt,
    const float* __restrict__ table, float* __restrict__ acc)
{
    constexpr int ROWS = 1 << SHIFT;
    constexpr int ROWM = ROWS - 1;
    extern __shared__ float lacc[];          // ROWS*64 floats
    const int tid = threadIdx.x;
    const int lane = tid & 63;
    const int wv = tid >> 6;                 // 0..7
    const int b = blockIdx.x;

    for (int i = tid; i < ROWS * 16; i += 512)
        ((float4*)lacc)[i] = float4{0.f, 0.f, 0.f, 0.f};
    __syncthreads();

    int n = cnt[b];
    if (n > BUCKET_CAP) n = BUCKET_CAP;
    const int2* bp = pairs + (size_t)b * BUCKET_CAP;

    int i = wv * 4;
    for (; i + 4 <= n; i += 32) {
        int2 p0 = bp[i], p1 = bp[i + 1], p2 = bp[i + 2], p3 = bp[i + 3];
        float v0 = table[(size_t)p0.y * 64 + lane];
        float v1 = table[(size_t)p1.y * 64 + lane];
        float v2 = table[(size_t)p2.y * 64 + lane];
        float v3 = table[(size_t)p3.y * 64 + lane];
        atomicAdd(&lacc[(p0.x & ROWM) * 64 + lane], v0);
        atomicAdd(&lacc[(p1.x & ROWM) * 64 + lane], v1);
        atomicAdd(&lacc[(p2.x & ROWM) * 64 + lane], v2);
        atomicAdd(&lacc[(p3.x & ROWM) * 64 + lane], v3);
    }
    for (int k = i; k < n && k < i + 4; ++k) {       // per-wave tail
        int2 p = bp[k];
        float v = table[(size_t)p.y * 64 + lane];
        atomicAdd(&lacc[(p.x & ROWM) * 64 + lane], v);
    }
    __syncthreads();

    // writeout: rows [b<<SHIFT, (b+1)<<SHIFT), coalesced float4
    float4* accG = (float4*)(acc + ((size_t)b << SHIFT) * 64);
    const float4* l4 = (const float4*)lacc;
    for (int j = tid; j < ROWS * 16; j += 512) {
        float4 v = l4[j];
        if (ADD_BASE) {
            float4 g = accG[j];
            v.x += g.x; v.y += g.y; v.z += g.z; v.w += g.w;
        }
        accG[j] = v;
    }
}

// out = relu(relu(in + b1) @ W2 + b2)   (64 -> 64); safe when out == in
__global__ __launch_bounds__(256) void mlp_obs(
    const float* __restrict__ in, const float* __restrict__ b1,
    const float* __restrict__ W2, const float* __restrict__ b2,
    float* __restrict__ out, int M)
{
    __shared__ float Ws[64 * 64];
    __shared__ float Hs[16 * 68];
    const int tid = threadIdx.x;
    for (int i = tid; i < 64 * 64 / 4; i += 256)
        ((float4*)Ws)[i] = ((const float4*)W2)[i];
    const int row0 = blockIdx.x * 16;
    {
        int r = tid >> 4, c4 = tid & 15;
        float4 v = ((const float4*)(in + (size_t)(row0 + r) * 64))[c4];
        float4 bb = ((const float4*)b1)[c4];
        v.x = fmaxf(v.x + bb.x, 0.f);
        v.y = fmaxf(v.y + bb.y, 0.f);
        v.z = fmaxf(v.z + bb.z, 0.f);
        v.w = fmaxf(v.w + bb.w, 0.f);
        *((float4*)(Hs + r * 68 + c4 * 4)) = v;
    }
    __syncthreads();
    const int rl = tid >> 4, cg = (tid & 15) * 4;
    float4 bb2 = *((const float4*)(b2 + cg));
    float a0 = bb2.x, a1 = bb2.y, a2 = bb2.z, a3 = bb2.w;
    const float* hr = Hs + rl * 68;
    #pragma unroll 8
    for (int k = 0; k < 64; ++k) {
        float xv = hr[k];
        float4 wv = *((const float4*)(Ws + k * 64 + cg));
        a0 = fmaf(xv, wv.x, a0);
        a1 = fmaf(xv, wv.y, a1);
        a2 = fmaf(xv, wv.z, a2);
        a3 = fmaf(xv, wv.w, a3);
    }
    float4 o;
    o.x = fmaxf(a0, 0.f); o.y = fmaxf(a1, 0.f);
    o.z = fmaxf(a2, 0.f); o.w = fmaxf(a3, 0.f);
    *((float4*)(out + (size_t)(row0 + rl) * 64 + cg)) = o;
}

// g = relu((x_task + acc2) @ W3 + b3); x2 = g @ W4 + b4
__global__ __launch_bounds__(256) void mlp_task(
    const float* __restrict__ x_task, const float* __restrict__ acc2,
    const float* __restrict__ W3, const float* __restrict__ b3,
    const float* __restrict__ W4, const float* __restrict__ b4,
    float* __restrict__ x2, int M)
{
    __shared__ float Ws[64 * 64];
    __shared__ float Ts[16 * 68];
    const int tid = threadIdx.x;
    for (int i = tid; i < 64 * 64 / 4; i += 256)
        ((float4*)Ws)[i] = ((const float4*)W3)[i];
    const int row0 = blockIdx.x * 16;
    {
        int r = tid >> 4, c4 = tid & 15;
        size_t off = (size_t)(row0 + r) * 64;
        float4 v = ((const float4*)(x_task + off))[c4];
        float4 u = ((const float4*)(acc2 + off))[c4];
        v.x += u.x; v.y += u.y; v.z += u.z; v.w += u.w;
        *((float4*)(Ts + r * 68 + c4 * 4)) = v;
    }
    __syncthreads();
    const int rl = tid >> 4, cg = (tid & 15) * 4;
    float4 bb = *((const float4*)(b3 + cg));
    float a0 = bb.x, a1 = bb.y, a2 = bb.z, a3 = bb.w;
    const float* tr = Ts + rl * 68;
    #pragma unroll 8
    for (int k = 0; k < 64; ++k) {
        float xv = tr[k];
        float4 wv = *((const float4*)(Ws + k * 64 + cg));
        a0 = fmaf(xv, wv.x, a0);
        a1 = fmaf(xv, wv.y, a1);
        a2 = fmaf(xv, wv.z, a2);
        a3 = fmaf(xv, wv.w, a3);
    }
    float4 w4 = *((const float4*)(W4 + cg));
    float p = fmaxf(a0, 0.f) * w4.x + fmaxf(a1, 0.f) * w4.y
            + fmaxf(a2, 0.f) * w4.z + fmaxf(a3, 0.f) * w4.w;
    p += __shfl_xor(p, 1);
    p += __shfl_xor(p, 2);
    p += __shfl_xor(p, 4);
    p += __shfl_xor(p, 8);
    if ((tid & 15) == 0)
        x2[row0 + rl] = p + b4[0];
}

// per-graph (32 contiguous task nodes) max/mean pool + critic MLP
__global__ __launch_bounds__(256) void pool_critic(
    const float* __restrict__ x2, const float* __restrict__ Wc1,
    const float* __restrict__ bc1, const float* __restrict__ Wc2,
    const float* __restrict__ bc2, float* __restrict__ out)
{
    int b = threadIdx.x;
    const float* p = x2 + b * 32;
    float mx = -1e30f, sm = 0.f;
    #pragma unroll
    for (int i = 0; i < 32; ++i) { float v = p[i]; mx = fmaxf(mx, v); sm += v; }
    float mn = sm * (1.f / 32.f);
    float o = bc2[0];
    #pragma unroll
    for (int j = 0; j < 8; ++j) {
        float t = fmaxf(mx * Wc1[j] + mn * Wc1[8 + j] + bc1[j], 0.f);
        o = fmaf(t, Wc2[j], o);
    }
    out[b] = o;
}

extern "C" void kernel_launch(void* const* d_in, const int* in_sizes, int n_in,
                              void* d_out, int out_size, void* d_ws, size_t ws_size,
                              hipStream_t stream)
{
    const float* x_goal = (const float*)d_in[0];
    const float* x_obs  = (const float*)d_in[1];
    const float* x_task = (const float*)d_in[2];
    const int* go_src = (const int*)d_in[3];
    const int* go_dst = (const int*)d_in[4];
    const int* ot_src = (const int*)d_in[5];
    const int* ot_dst = (const int*)d_in[6];
    const float* W1  = (const float*)d_in[8];
    const float* b1  = (const float*)d_in[9];
    const float* W2  = (const float*)d_in[10];
    const float* b2  = (const float*)d_in[11];
    const float* W3  = (const float*)d_in[12];
    const float* b3  = (const float*)d_in[13];
    const float* W4  = (const float*)d_in[14];
    const float* b4  = (const float*)d_in[15];
    const float* Wc1 = (const float*)d_in[16];
    const float* bc1 = (const float*)d_in[17];
    const float* Wc2 = (const float*)d_in[18];
    const float* bc2 = (const float*)d_in[19];
    float* out = (float*)d_out;

    const int N_GOAL = 16384, N_OBS = 65536, N_TASK = 8192;
    const int E1 = in_sizes[3], E2 = in_sizes[5];

    // workspace layout (~35.7 MB; <= 38 MB proven usable in round 1)
    char* w = (char*)d_ws;
    float* obs   = (float*)w;   w += (size_t)N_OBS * 64 * 4;        // 16 MB
    float* xg1   = (float*)w;   w += (size_t)N_GOAL * 64 * 4;       //  4 MB
    float* acc2  = (float*)w;   w += (size_t)N_TASK * 64 * 4;       //  2 MB
    float* x2    = (float*)w;   w += (size_t)N_TASK * 4;            // 32 KB
    int2*  pairs = (int2*)w;    w += (size_t)256 * BUCKET_CAP * 8;  // 12 MB (shared by both stages)
    int*   gcur1 = (int*)w;     w += 256 * 4;
    int*   gcur2 = (int*)w;     w += 256 * 4;

    hipMemsetAsync(gcur1, 0, 512 * 4, stream);   // zeroes gcur1 + gcur2

    // stage-1 binning + dense GEMMs (independent)
    bin_edges<8><<<E1 / 4096, 256, 0, stream>>>(go_src, go_dst, gcur1, pairs);
    gemm_k128<<<N_GOAL / 16, 256, 0, stream>>>(x_goal, W1, xg1, N_GOAL);
    gemm_k128<<<N_OBS / 16, 256, 0, stream>>>(x_obs, W1, obs, N_OBS);

    // stage-1 gather: obs += sum over bucket edges of xg1[src]
    gather_bucket<8, true><<<256, 512, 256 * 64 * 4, stream>>>(pairs, gcur1, xg1, obs);
    mlp_obs<<<N_OBS / 16, 256, 0, stream>>>(obs, b1, W2, b2, obs, N_OBS);

    // stage-2 binning (reuses pair buffer; stream order guarantees safety)
    bin_edges<5><<<E2 / 4096, 256, 0, stream>>>(ot_src, ot_dst, gcur2, pairs);
    gather_bucket<5, false><<<256, 512, 32 * 64 * 4, stream>>>(pairs, gcur2, obs, acc2);

    mlp_task<<<N_TASK / 16, 256, 0, stream>>>(x_task, acc2, W3, b3, W4, b4, x2, N_TASK);
    pool_critic<<<1, 256, 0, stream>>>(x2, Wc1, bc1, Wc2, bc2, out);
}

// Round 4
// 270.737 us; speedup vs baseline: 3.3340x; 3.3340x over previous
//
#include <hip/hip_runtime.h>
#include <hip/hip_bf16.h>

// ---------------------------------------------------------------------------
// Round-4 structure:
//   pass A (bin_edges): 256 blocks LDS-histogram 4096 edges into 512 coarse
//     buckets, reserve contiguous runs with ONE global atomic per
//     (block,bucket), write (dst,src) pairs coalesced.  [round-3, kept]
//   pass B (gather_sorted): per bucket, in-LDS counting sort by row, then
//     each wave accumulates whole rows in REGISTERS (no LDS float atomics —
//     round-3's 354us latency wall) at 32 waves/CU.
//   Dense parts: W1 pushed through aggregation (GEMMs before scatter);
//   mlp_task + pooling + critic fused into one kernel.
// ---------------------------------------------------------------------------

#define NB 512            // coarse buckets per stage
#define BUCKET_CAP 2816   // mean 2048 edges/bucket, sigma~45 -> mean+17sigma

// out[M,64] = X[M,128] @ W[128,64]   (no bias)
__global__ __launch_bounds__(256) void gemm_k128(
    const float* __restrict__ X, const float* __restrict__ W,
    float* __restrict__ out, int M)
{
    __shared__ float Ws[128 * 64];
    __shared__ float Xs[16 * 132];
    const int tid = threadIdx.x;
    for (int i = tid; i < 128 * 64 / 4; i += 256)
        ((float4*)Ws)[i] = ((const float4*)W)[i];
    const int row0 = blockIdx.x * 16;
    for (int i = tid; i < 16 * 32; i += 256) {
        int r = i >> 5, c4 = i & 31;
        float4 v = ((const float4*)(X + (size_t)(row0 + r) * 128))[c4];
        *((float4*)(Xs + r * 132 + c4 * 4)) = v;
    }
    __syncthreads();
    const int rl = tid >> 4;
    const int cg = (tid & 15) * 4;
    float a0 = 0.f, a1 = 0.f, a2 = 0.f, a3 = 0.f;
    const float* xr = Xs + rl * 132;
    #pragma unroll 8
    for (int k = 0; k < 128; ++k) {
        float xv = xr[k];
        float4 wv = *((const float4*)(Ws + k * 64 + cg));
        a0 = fmaf(xv, wv.x, a0);
        a1 = fmaf(xv, wv.y, a1);
        a2 = fmaf(xv, wv.z, a2);
        a3 = fmaf(xv, wv.w, a3);
    }
    float4 o; o.x = a0; o.y = a1; o.z = a2; o.w = a3;
    *((float4*)(out + (size_t)(row0 + rl) * 64 + cg)) = o;
}

// ------------------- coarse binning (pass A) ------------------------------
template <int BSH>
__global__ __launch_bounds__(256) void bin_edges(
    const int* __restrict__ src, const int* __restrict__ dst,
    int* __restrict__ gcur, int2* __restrict__ pairs)
{
    __shared__ int hist[NB];
    __shared__ int cur[NB];
    const int tid = threadIdx.x;
    for (int i = tid; i < NB; i += 256) hist[i] = 0;
    __syncthreads();
    const int base = blockIdx.x * 4096;
    const int4* d4 = (const int4*)(dst + base);
    const int4* s4 = (const int4*)(src + base);
    int4 dv[4];
    #pragma unroll
    for (int k = 0; k < 4; ++k) {
        dv[k] = d4[k * 256 + tid];
        atomicAdd(&hist[dv[k].x >> BSH], 1);
        atomicAdd(&hist[dv[k].y >> BSH], 1);
        atomicAdd(&hist[dv[k].z >> BSH], 1);
        atomicAdd(&hist[dv[k].w >> BSH], 1);
    }
    __syncthreads();
    for (int i = tid; i < NB; i += 256)
        cur[i] = atomicAdd(&gcur[i], hist[i]);     // reserve contiguous run
    __syncthreads();
    #pragma unroll
    for (int k = 0; k < 4; ++k) {
        int4 sv = s4[k * 256 + tid];
        int d, s, b, p;
        d = dv[k].x; s = sv.x; b = d >> BSH; p = atomicAdd(&cur[b], 1);
        if (p < BUCKET_CAP) pairs[(size_t)b * BUCKET_CAP + p] = make_int2(d, s);
        d = dv[k].y; s = sv.y; b = d >> BSH; p = atomicAdd(&cur[b], 1);
        if (p < BUCKET_CAP) pairs[(size_t)b * BUCKET_CAP + p] = make_int2(d, s);
        d = dv[k].z; s = sv.z; b = d >> BSH; p = atomicAdd(&cur[b], 1);
        if (p < BUCKET_CAP) pairs[(size_t)b * BUCKET_CAP + p] = make_int2(d, s);
        d = dv[k].w; s = sv.w; b = d >> BSH; p = atomicAdd(&cur[b], 1);
        if (p < BUCKET_CAP) pairs[(size_t)b * BUCKET_CAP + p] = make_int2(d, s);
    }
}

// ------------------- sorted bucket gather (pass B) ------------------------
// One 1024-thread WG (16 waves) per bucket.  In-LDS counting sort of the
// bucket's edges by row, then each wave accumulates whole rows in registers:
// lane = column, wave-uniform ssrc reads broadcast, 4 independent acc chains,
// one coalesced 256B read-modify-write per row.  No atomics in the hot path.
template <int BSH, bool ADD_BASE>
__global__ __launch_bounds__(1024) void gather_sorted(
    const int2* __restrict__ pairs, const int* __restrict__ cnt,
    const float* __restrict__ table, float* __restrict__ outb)
{
    constexpr int ROWS = 1 << BSH;
    constexpr int ROWM = ROWS - 1;
    __shared__ int ssrc[BUCKET_CAP];
    __shared__ int offs[ROWS + 1];
    __shared__ int cur[ROWS];
    __shared__ int sc[ROWS];
    const int tid = threadIdx.x;
    const int b = blockIdx.x;

    for (int i = tid; i < ROWS; i += 1024) cur[i] = 0;
    __syncthreads();
    int n = cnt[b];
    if (n > BUCKET_CAP) n = BUCKET_CAP;
    const int2* bp = pairs + (size_t)b * BUCKET_CAP;

    // 1) histogram rows
    for (int i = tid; i < n; i += 1024)
        atomicAdd(&cur[bp[i].x & ROWM], 1);
    __syncthreads();
    // 2) scan (Hillis-Steele over ROWS <= 128)
    if (tid < ROWS) sc[tid] = cur[tid];
    __syncthreads();
    for (int off = 1; off < ROWS; off <<= 1) {
        int v = 0;
        if (tid < ROWS && tid >= off) v = sc[tid - off];
        __syncthreads();
        if (tid < ROWS) sc[tid] += v;
        __syncthreads();
    }
    if (tid < ROWS) {
        int ex = (tid == 0) ? 0 : sc[tid - 1];
        offs[tid] = ex;
        cur[tid] = ex;
        if (tid == ROWS - 1) offs[ROWS] = sc[tid];
    }
    __syncthreads();
    // 3) scatter src ids into row-sorted LDS order
    for (int i = tid; i < n; i += 1024) {
        int2 p = bp[i];
        int pos = atomicAdd(&cur[p.x & ROWM], 1);
        ssrc[pos] = p.y;
    }
    __syncthreads();
    // 4) per-row register gather
    const int wv = tid >> 6;
    const int lane = tid & 63;
    for (int r = wv; r < ROWS; r += 16) {
        int beg = offs[r], end = offs[r + 1];
        float a0 = 0.f, a1 = 0.f, a2 = 0.f, a3 = 0.f;
        int e = beg;
        for (; e + 4 <= end; e += 4) {
            int s0 = ssrc[e], s1 = ssrc[e + 1], s2 = ssrc[e + 2], s3 = ssrc[e + 3];
            a0 += table[(size_t)s0 * 64 + lane];
            a1 += table[(size_t)s1 * 64 + lane];
            a2 += table[(size_t)s2 * 64 + lane];
            a3 += table[(size_t)s3 * 64 + lane];
        }
        for (; e < end; ++e)
            a0 += table[(size_t)ssrc[e] * 64 + lane];
        float acc = (a0 + a1) + (a2 + a3);
        size_t gi = (((size_t)b << BSH) + r) * 64 + lane;
        if (ADD_BASE) acc += outb[gi];
        outb[gi] = acc;
    }
}

// out = relu(relu(in + b1) @ W2 + b2)   (64 -> 64); safe when out == in
__global__ __launch_bounds__(256) void mlp_obs(
    const float* __restrict__ in, const float* __restrict__ b1,
    const float* __restrict__ W2, const float* __restrict__ b2,
    float* __restrict__ out, int M)
{
    __shared__ float Ws[64 * 64];
    __shared__ float Hs[16 * 68];
    const int tid = threadIdx.x;
    for (int i = tid; i < 64 * 64 / 4; i += 256)
        ((float4*)Ws)[i] = ((const float4*)W2)[i];
    const int row0 = blockIdx.x * 16;
    {
        int r = tid >> 4, c4 = tid & 15;
        float4 v = ((const float4*)(in + (size_t)(row0 + r) * 64))[c4];
        float4 bb = ((const float4*)b1)[c4];
        v.x = fmaxf(v.x + bb.x, 0.f);
        v.y = fmaxf(v.y + bb.y, 0.f);
        v.z = fmaxf(v.z + bb.z, 0.f);
        v.w = fmaxf(v.w + bb.w, 0.f);
        *((float4*)(Hs + r * 68 + c4 * 4)) = v;
    }
    __syncthreads();
    const int rl = tid >> 4, cg = (tid & 15) * 4;
    float4 bb2 = *((const float4*)(b2 + cg));
    float a0 = bb2.x, a1 = bb2.y, a2 = bb2.z, a3 = bb2.w;
    const float* hr = Hs + rl * 68;
    #pragma unroll 8
    for (int k = 0; k < 64; ++k) {
        float xv = hr[k];
        float4 wv = *((const float4*)(Ws + k * 64 + cg));
        a0 = fmaf(xv, wv.x, a0);
        a1 = fmaf(xv, wv.y, a1);
        a2 = fmaf(xv, wv.z, a2);
        a3 = fmaf(xv, wv.w, a3);
    }
    float4 o;
    o.x = fmaxf(a0, 0.f); o.y = fmaxf(a1, 0.f);
    o.z = fmaxf(a2, 0.f); o.w = fmaxf(a3, 0.f);
    *((float4*)(out + (size_t)(row0 + rl) * 64 + cg)) = o;
}

// One block = one graph (32 task rows): g = relu((x_task+acc2)@W3+b3);
// x2 = g@W4+b4; then max/mean pool over the 32 rows + critic MLP -> out[b].
__global__ __launch_bounds__(512) void mlp_task_pool(
    const float* __restrict__ x_task, const float* __restrict__ acc2,
    const float* __restrict__ W3, const float* __restrict__ b3,
    const float* __restrict__ W4, const float* __restrict__ b4,
    const float* __restrict__ Wc1, const float* __restrict__ bc1,
    const float* __restrict__ Wc2, const float* __restrict__ bc2,
    float* __restrict__ out)
{
    __shared__ float Ws[64 * 64];
    __shared__ float Ts[32 * 68];
    __shared__ float xrow[32];
    const int tid = threadIdx.x;
    for (int i = tid; i < 64 * 64 / 4; i += 512)
        ((float4*)Ws)[i] = ((const float4*)W3)[i];
    const int row0 = blockIdx.x * 32;
    {
        int r = tid >> 4, c4 = tid & 15;
        size_t off = (size_t)(row0 + r) * 64;
        float4 v = ((const float4*)(x_task + off))[c4];
        float4 u = ((const float4*)(acc2 + off))[c4];
        v.x += u.x; v.y += u.y; v.z += u.z; v.w += u.w;
        *((float4*)(Ts + r * 68 + c4 * 4)) = v;
    }
    __syncthreads();
    const int rl = tid >> 4, cg = (tid & 15) * 4;
    float4 bb = *((const float4*)(b3 + cg));
    float a0 = bb.x, a1 = bb.y, a2 = bb.z, a3 = bb.w;
    const float* tr = Ts + rl * 68;
    #pragma unroll 8
    for (int k = 0; k < 64; ++k) {
        float xv = tr[k];
        float4 wv = *((const float4*)(Ws + k * 64 + cg));
        a0 = fmaf(xv, wv.x, a0);
        a1 = fmaf(xv, wv.y, a1);
        a2 = fmaf(xv, wv.z, a2);
        a3 = fmaf(xv, wv.w, a3);
    }
    float4 w4 = *((const float4*)(W4 + cg));
    float p = fmaxf(a0, 0.f) * w4.x + fmaxf(a1, 0.f) * w4.y
            + fmaxf(a2, 0.f) * w4.z + fmaxf(a3, 0.f) * w4.w;
    p += __shfl_xor(p, 1);
    p += __shfl_xor(p, 2);
    p += __shfl_xor(p, 4);
    p += __shfl_xor(p, 8);
    if ((tid & 15) == 0) xrow[rl] = p + b4[0];
    __syncthreads();
    if (tid == 0) {
        float mx = -1e30f, sm = 0.f;
        #pragma unroll
        for (int i = 0; i < 32; ++i) { float v = xrow[i]; mx = fmaxf(mx, v); sm += v; }
        float mn = sm * (1.f / 32.f);
        float o = bc2[0];
        #pragma unroll
        for (int j = 0; j < 8; ++j) {
            float t = fmaxf(mx * Wc1[j] + mn * Wc1[8 + j] + bc1[j], 0.f);
            o = fmaf(t, Wc2[j], o);
        }
        out[blockIdx.x] = o;
    }
}

extern "C" void kernel_launch(void* const* d_in, const int* in_sizes, int n_in,
                              void* d_out, int out_size, void* d_ws, size_t ws_size,
                              hipStream_t stream)
{
    const float* x_goal = (const float*)d_in[0];
    const float* x_obs  = (const float*)d_in[1];
    const float* x_task = (const float*)d_in[2];
    const int* go_src = (const int*)d_in[3];
    const int* go_dst = (const int*)d_in[4];
    const int* ot_src = (const int*)d_in[5];
    const int* ot_dst = (const int*)d_in[6];
    const float* W1  = (const float*)d_in[8];
    const float* b1  = (const float*)d_in[9];
    const float* W2  = (const float*)d_in[10];
    const float* b2  = (const float*)d_in[11];
    const float* W3  = (const float*)d_in[12];
    const float* b3  = (const float*)d_in[13];
    const float* W4  = (const float*)d_in[14];
    const float* b4  = (const float*)d_in[15];
    const float* Wc1 = (const float*)d_in[16];
    const float* bc1 = (const float*)d_in[17];
    const float* Wc2 = (const float*)d_in[18];
    const float* bc2 = (const float*)d_in[19];
    float* out = (float*)d_out;

    const int N_GOAL = 16384, N_OBS = 65536, N_TASK = 8192;
    const int E1 = in_sizes[3], E2 = in_sizes[5];

    // workspace (~33.6 MB)
    char* w = (char*)d_ws;
    float* obs   = (float*)w;   w += (size_t)N_OBS * 64 * 4;          // 16 MB
    float* xg1   = (float*)w;   w += (size_t)N_GOAL * 64 * 4;         //  4 MB
    float* acc2  = (float*)w;   w += (size_t)N_TASK * 64 * 4;         //  2 MB
    int2*  pairs = (int2*)w;    w += (size_t)NB * BUCKET_CAP * 8;     // 11.5 MB (both stages)
    int*   gcur1 = (int*)w;     w += NB * 4;
    int*   gcur2 = (int*)w;     w += NB * 4;

    hipMemsetAsync(gcur1, 0, 2 * NB * 4, stream);

    // stage 1: bin (65536 rows -> 512 buckets of 128), dense GEMMs, gather
    bin_edges<7><<<E1 / 4096, 256, 0, stream>>>(go_src, go_dst, gcur1, pairs);
    gemm_k128<<<N_GOAL / 16, 256, 0, stream>>>(x_goal, W1, xg1, N_GOAL);
    gemm_k128<<<N_OBS / 16, 256, 0, stream>>>(x_obs, W1, obs, N_OBS);
    gather_sorted<7, true><<<NB, 1024, 0, stream>>>(pairs, gcur1, xg1, obs);
    mlp_obs<<<N_OBS / 16, 256, 0, stream>>>(obs, b1, W2, b2, obs, N_OBS);

    // stage 2: bin (8192 rows -> 512 buckets of 16), gather, fused tail
    bin_edges<4><<<E2 / 4096, 256, 0, stream>>>(ot_src, ot_dst, gcur2, pairs);
    gather_sorted<4, false><<<NB, 1024, 0, stream>>>(pairs, gcur2, obs, acc2);
    mlp_task_pool<<<N_TASK / 32, 512, 0, stream>>>(x_task, acc2, W3, b3, W4, b4,
                                                   Wc1, bc1, Wc2, bc2, out);
}

// Round 5
// 264.228 us; speedup vs baseline: 3.4161x; 1.0246x over previous
//
#include <hip/hip_runtime.h>
#include <hip/hip_bf16.h>

// ---------------------------------------------------------------------------
// Round-5 structure (fusion + packed pairs):
//   bin_edges<BSH>: 256 blocks LDS-histogram 4096 edges into 512 coarse
//     buckets, reserve contiguous runs (1 global atomic per block-bucket),
//     write PACKED (row_in_bucket<<17 | src) ints coalesced.
//   gather_mlp_obs: per bucket (128 obs rows), in-LDS counting sort by row,
//     per-row register accumulate (lane=column), += base (x_obs@W1), then the
//     FUSED obs-MLP: relu(+b1) -> LDS row buffer -> matvec W2 -> relu -> x1.
//   gather_mlp_task: per bucket (16 task rows), same sort, 8-chain register
//     accumulate from x1, += x_task, FUSED task-MLP: @W3+b3, relu, dot W4,
//     wave-reduce -> x2[row] scalar.
//   pool_critic: 256 graphs (32 rows each) max/mean pool + critic MLP.
//   W1 pushed through the linear aggregation (GEMMs before gather).
// ---------------------------------------------------------------------------

#define NB 512            // coarse buckets per stage
#define BUCKET_CAP 2816   // mean 2048 edges/bucket, sigma~45 -> mean+17sigma

// out[M,64] = X[M,128] @ W[128,64]   (no bias)
__global__ __launch_bounds__(256) void gemm_k128(
    const float* __restrict__ X, const float* __restrict__ W,
    float* __restrict__ out, int M)
{
    __shared__ float Ws[128 * 64];
    __shared__ float Xs[16 * 132];
    const int tid = threadIdx.x;
    for (int i = tid; i < 128 * 64 / 4; i += 256)
        ((float4*)Ws)[i] = ((const float4*)W)[i];
    const int row0 = blockIdx.x * 16;
    for (int i = tid; i < 16 * 32; i += 256) {
        int r = i >> 5, c4 = i & 31;
        float4 v = ((const float4*)(X + (size_t)(row0 + r) * 128))[c4];
        *((float4*)(Xs + r * 132 + c4 * 4)) = v;
    }
    __syncthreads();
    const int rl = tid >> 4;
    const int cg = (tid & 15) * 4;
    float a0 = 0.f, a1 = 0.f, a2 = 0.f, a3 = 0.f;
    const float* xr = Xs + rl * 132;
    #pragma unroll 8
    for (int k = 0; k < 128; ++k) {
        float xv = xr[k];
        float4 wv = *((const float4*)(Ws + k * 64 + cg));
        a0 = fmaf(xv, wv.x, a0);
        a1 = fmaf(xv, wv.y, a1);
        a2 = fmaf(xv, wv.z, a2);
        a3 = fmaf(xv, wv.w, a3);
    }
    float4 o; o.x = a0; o.y = a1; o.z = a2; o.w = a3;
    *((float4*)(out + (size_t)(row0 + rl) * 64 + cg)) = o;
}

// ------------------- coarse binning (pass A, packed) ----------------------
template <int BSH>
__global__ __launch_bounds__(256) void bin_edges(
    const int* __restrict__ src, const int* __restrict__ dst,
    int* __restrict__ gcur, int* __restrict__ pairs)
{
    constexpr int ROWM = (1 << BSH) - 1;
    __shared__ int hist[NB];
    __shared__ int cur[NB];
    const int tid = threadIdx.x;
    for (int i = tid; i < NB; i += 256) hist[i] = 0;
    __syncthreads();
    const int base = blockIdx.x * 4096;
    const int4* d4 = (const int4*)(dst + base);
    const int4* s4 = (const int4*)(src + base);
    int4 dv[4];
    #pragma unroll
    for (int k = 0; k < 4; ++k) {
        dv[k] = d4[k * 256 + tid];
        atomicAdd(&hist[dv[k].x >> BSH], 1);
        atomicAdd(&hist[dv[k].y >> BSH], 1);
        atomicAdd(&hist[dv[k].z >> BSH], 1);
        atomicAdd(&hist[dv[k].w >> BSH], 1);
    }
    __syncthreads();
    for (int i = tid; i < NB; i += 256)
        cur[i] = atomicAdd(&gcur[i], hist[i]);     // reserve contiguous run
    __syncthreads();
    #pragma unroll
    for (int k = 0; k < 4; ++k) {
        int4 sv = s4[k * 256 + tid];
        int d, s, b, p;
        d = dv[k].x; s = sv.x; b = d >> BSH; p = atomicAdd(&cur[b], 1);
        if (p < BUCKET_CAP) pairs[(size_t)b * BUCKET_CAP + p] = ((d & ROWM) << 17) | s;
        d = dv[k].y; s = sv.y; b = d >> BSH; p = atomicAdd(&cur[b], 1);
        if (p < BUCKET_CAP) pairs[(size_t)b * BUCKET_CAP + p] = ((d & ROWM) << 17) | s;
        d = dv[k].z; s = sv.z; b = d >> BSH; p = atomicAdd(&cur[b], 1);
        if (p < BUCKET_CAP) pairs[(size_t)b * BUCKET_CAP + p] = ((d & ROWM) << 17) | s;
        d = dv[k].w; s = sv.w; b = d >> BSH; p = atomicAdd(&cur[b], 1);
        if (p < BUCKET_CAP) pairs[(size_t)b * BUCKET_CAP + p] = ((d & ROWM) << 17) | s;
    }
}

// ------------- stage-1 gather + fused obs MLP (pass B) --------------------
// One 1024-thread WG per bucket of 128 obs rows.  In-LDS counting sort by
// row, per-row register accumulate (lane = column, 4 chains), += base
// (x_obs@W1), then h=relu(+b1) staged via per-wave LDS row (same-wave, no
// barrier), matvec with LDS W2 (broadcast read + 2-way-free bank stride),
// x1 = relu(+b2).  No atomics in the hot path.
__global__ __launch_bounds__(1024) void gather_mlp_obs(
    const int* __restrict__ pairs, const int* __restrict__ cnt,
    const float* __restrict__ xg1, const float* __restrict__ obs,
    const float* __restrict__ b1, const float* __restrict__ W2,
    const float* __restrict__ b2, float* __restrict__ x1)
{
    constexpr int ROWS = 128;
    __shared__ int ssrc[BUCKET_CAP];
    __shared__ int offs[ROWS + 1];
    __shared__ int cur[ROWS];
    __shared__ int sc[ROWS];
    __shared__ float W2s[64 * 64];
    __shared__ float hb[16 * 64];
    const int tid = threadIdx.x;
    const int b = blockIdx.x;

    ((float4*)W2s)[tid] = ((const float4*)W2)[tid];      // 4096 floats, 1/thread
    if (tid < ROWS) cur[tid] = 0;
    __syncthreads();
    int n = cnt[b];
    if (n > BUCKET_CAP) n = BUCKET_CAP;
    const int* bp = pairs + (size_t)b * BUCKET_CAP;

    // 1) histogram rows
    for (int i = tid; i < n; i += 1024)
        atomicAdd(&cur[bp[i] >> 17], 1);
    __syncthreads();
    // 2) scan
    if (tid < ROWS) sc[tid] = cur[tid];
    __syncthreads();
    for (int off = 1; off < ROWS; off <<= 1) {
        int v = 0;
        if (tid < ROWS && tid >= off) v = sc[tid - off];
        __syncthreads();
        if (tid < ROWS) sc[tid] += v;
        __syncthreads();
    }
    if (tid < ROWS) {
        int ex = (tid == 0) ? 0 : sc[tid - 1];
        offs[tid] = ex;
        cur[tid] = ex;
        if (tid == ROWS - 1) offs[ROWS] = sc[tid];
    }
    __syncthreads();
    // 3) scatter src into row-sorted order
    for (int i = tid; i < n; i += 1024) {
        int p = bp[i];
        int pos = atomicAdd(&cur[p >> 17], 1);
        ssrc[pos] = p & 0x1FFFF;
    }
    __syncthreads();
    // 4) per-row register gather + fused MLP
    const int wv = tid >> 6;
    const int lane = tid & 63;
    const float bb1 = b1[lane];
    const float bb2 = b2[lane];
    float* hp = hb + wv * 64;
    for (int r = wv; r < ROWS; r += 16) {
        int beg = offs[r], end = offs[r + 1];
        float a0 = 0.f, a1 = 0.f, a2 = 0.f, a3 = 0.f;
        int e = beg;
        for (; e + 4 <= end; e += 4) {
            int s0 = ssrc[e], s1 = ssrc[e + 1], s2 = ssrc[e + 2], s3 = ssrc[e + 3];
            a0 += xg1[(size_t)s0 * 64 + lane];
            a1 += xg1[(size_t)s1 * 64 + lane];
            a2 += xg1[(size_t)s2 * 64 + lane];
            a3 += xg1[(size_t)s3 * 64 + lane];
        }
        for (; e < end; ++e)
            a0 += xg1[(size_t)ssrc[e] * 64 + lane];
        size_t gi = (((size_t)b * ROWS) + r) * 64 + lane;
        float acc = (a0 + a1) + (a2 + a3) + obs[gi];     // += x_obs@W1 base
        hp[lane] = fmaxf(acc + bb1, 0.f);                // same-wave stage
        float a = bb2;
        #pragma unroll 16
        for (int k = 0; k < 64; ++k)
            a = fmaf(hp[k], W2s[k * 64 + lane], a);
        x1[gi] = fmaxf(a, 0.f);
    }
}

// ------------- stage-2 gather + fused task MLP (pass B) -------------------
// One 1024-thread WG per bucket of 16 task rows (1 row per wave).  8-chain
// register accumulate from x1, += x_task, fused W3 matvec + relu + W4 dot +
// wave reduce -> scalar x2[row].
__global__ __launch_bounds__(1024) void gather_mlp_task(
    const int* __restrict__ pairs, const int* __restrict__ cnt,
    const float* __restrict__ x1, const float* __restrict__ x_task,
    const float* __restrict__ W3, const float* __restrict__ b3,
    const float* __restrict__ W4, const float* __restrict__ b4,
    float* __restrict__ x2)
{
    constexpr int ROWS = 16;
    __shared__ int ssrc[BUCKET_CAP];
    __shared__ int offs[ROWS + 1];
    __shared__ int cur[ROWS];
    __shared__ int sc[ROWS];
    __shared__ float W3s[64 * 64];
    __shared__ float hb[16 * 64];
    const int tid = threadIdx.x;
    const int b = blockIdx.x;

    ((float4*)W3s)[tid] = ((const float4*)W3)[tid];
    if (tid < ROWS) cur[tid] = 0;
    __syncthreads();
    int n = cnt[b];
    if (n > BUCKET_CAP) n = BUCKET_CAP;
    const int* bp = pairs + (size_t)b * BUCKET_CAP;

    for (int i = tid; i < n; i += 1024)
        atomicAdd(&cur[bp[i] >> 17], 1);
    __syncthreads();
    if (tid < ROWS) sc[tid] = cur[tid];
    __syncthreads();
    for (int off = 1; off < ROWS; off <<= 1) {
        int v = 0;
        if (tid < ROWS && tid >= off) v = sc[tid - off];
        __syncthreads();
        if (tid < ROWS) sc[tid] += v;
        __syncthreads();
    }
    if (tid < ROWS) {
        int ex = (tid == 0) ? 0 : sc[tid - 1];
        offs[tid] = ex;
        cur[tid] = ex;
        if (tid == ROWS - 1) offs[ROWS] = sc[tid];
    }
    __syncthreads();
    for (int i = tid; i < n; i += 1024) {
        int p = bp[i];
        int pos = atomicAdd(&cur[p >> 17], 1);
        ssrc[pos] = p & 0x1FFFF;
    }
    __syncthreads();

    const int wv = tid >> 6;        // 16 waves == 16 rows
    const int lane = tid & 63;
    const int r = wv;
    const int row = b * ROWS + r;
    int beg = offs[r], end = offs[r + 1];
    float a0 = 0.f, a1 = 0.f, a2 = 0.f, a3 = 0.f;
    float a4 = 0.f, a5 = 0.f, a6 = 0.f, a7 = 0.f;
    int e = beg;
    for (; e + 8 <= end; e += 8) {
        int s0 = ssrc[e],     s1 = ssrc[e + 1], s2 = ssrc[e + 2], s3 = ssrc[e + 3];
        int s4 = ssrc[e + 4], s5 = ssrc[e + 5], s6 = ssrc[e + 6], s7 = ssrc[e + 7];
        a0 += x1[(size_t)s0 * 64 + lane];
        a1 += x1[(size_t)s1 * 64 + lane];
        a2 += x1[(size_t)s2 * 64 + lane];
        a3 += x1[(size_t)s3 * 64 + lane];
        a4 += x1[(size_t)s4 * 64 + lane];
        a5 += x1[(size_t)s5 * 64 + lane];
        a6 += x1[(size_t)s6 * 64 + lane];
        a7 += x1[(size_t)s7 * 64 + lane];
    }
    for (; e < end; ++e)
        a0 += x1[(size_t)ssrc[e] * 64 + lane];
    float t = ((a0 + a1) + (a2 + a3)) + ((a4 + a5) + (a6 + a7))
            + x_task[(size_t)row * 64 + lane];
    float* hp = hb + wv * 64;
    hp[lane] = t;                                  // same-wave stage (no relu)
    float a = b3[lane];
    #pragma unroll 16
    for (int k = 0; k < 64; ++k)
        a = fmaf(hp[k], W3s[k * 64 + lane], a);
    float p = fmaxf(a, 0.f) * W4[lane];
    p += __shfl_xor(p, 1);
    p += __shfl_xor(p, 2);
    p += __shfl_xor(p, 4);
    p += __shfl_xor(p, 8);
    p += __shfl_xor(p, 16);
    p += __shfl_xor(p, 32);
    if (lane == 0)
        x2[row] = p + b4[0];
}

// per-graph (32 contiguous task nodes) max/mean pool + critic MLP
__global__ __launch_bounds__(256) void pool_critic(
    const float* __restrict__ x2, const float* __restrict__ Wc1,
    const float* __restrict__ bc1, const float* __restrict__ Wc2,
    const float* __restrict__ bc2, float* __restrict__ out)
{
    int b = threadIdx.x;
    const float* p = x2 + b * 32;
    float mx = -1e30f, sm = 0.f;
    #pragma unroll
    for (int i = 0; i < 32; ++i) { float v = p[i]; mx = fmaxf(mx, v); sm += v; }
    float mn = sm * (1.f / 32.f);
    float o = bc2[0];
    #pragma unroll
    for (int j = 0; j < 8; ++j) {
        float t = fmaxf(mx * Wc1[j] + mn * Wc1[8 + j] + bc1[j], 0.f);
        o = fmaf(t, Wc2[j], o);
    }
    out[b] = o;
}

extern "C" void kernel_launch(void* const* d_in, const int* in_sizes, int n_in,
                              void* d_out, int out_size, void* d_ws, size_t ws_size,
                              hipStream_t stream)
{
    const float* x_goal = (const float*)d_in[0];
    const float* x_obs  = (const float*)d_in[1];
    const float* x_task = (const float*)d_in[2];
    const int* go_src = (const int*)d_in[3];
    const int* go_dst = (const int*)d_in[4];
    const int* ot_src = (const int*)d_in[5];
    const int* ot_dst = (const int*)d_in[6];
    const float* W1  = (const float*)d_in[8];
    const float* b1  = (const float*)d_in[9];
    const float* W2  = (const float*)d_in[10];
    const float* b2  = (const float*)d_in[11];
    const float* W3  = (const float*)d_in[12];
    const float* b3  = (const float*)d_in[13];
    const float* W4  = (const float*)d_in[14];
    const float* b4  = (const float*)d_in[15];
    const float* Wc1 = (const float*)d_in[16];
    const float* bc1 = (const float*)d_in[17];
    const float* Wc2 = (const float*)d_in[18];
    const float* bc2 = (const float*)d_in[19];
    float* out = (float*)d_out;

    const int N_GOAL = 16384, N_OBS = 65536, N_TASK = 8192;
    const int E1 = in_sizes[3], E2 = in_sizes[5];

    // workspace (~48 MB of the 256 MiB available)
    char* w = (char*)d_ws;
    float* obs    = (float*)w;  w += (size_t)N_OBS * 64 * 4;        // 16 MB
    float* x1     = (float*)w;  w += (size_t)N_OBS * 64 * 4;        // 16 MB
    float* xg1    = (float*)w;  w += (size_t)N_GOAL * 64 * 4;       //  4 MB
    float* x2     = (float*)w;  w += (size_t)N_TASK * 4;            // 32 KB
    int*   pairs1 = (int*)w;    w += (size_t)NB * BUCKET_CAP * 4;   //  5.8 MB
    int*   pairs2 = (int*)w;    w += (size_t)NB * BUCKET_CAP * 4;   //  5.8 MB
    int*   gcur1  = (int*)w;    w += NB * 4;
    int*   gcur2  = (int*)w;    w += NB * 4;

    hipMemsetAsync(gcur1, 0, 2 * NB * 4, stream);   // zeroes gcur1 + gcur2

    bin_edges<7><<<E1 / 4096, 256, 0, stream>>>(go_src, go_dst, gcur1, pairs1);
    bin_edges<4><<<E2 / 4096, 256, 0, stream>>>(ot_src, ot_dst, gcur2, pairs2);
    gemm_k128<<<N_GOAL / 16, 256, 0, stream>>>(x_goal, W1, xg1, N_GOAL);
    gemm_k128<<<N_OBS / 16, 256, 0, stream>>>(x_obs, W1, obs, N_OBS);
    gather_mlp_obs<<<NB, 1024, 0, stream>>>(pairs1, gcur1, xg1, obs, b1, W2, b2, x1);
    gather_mlp_task<<<NB, 1024, 0, stream>>>(pairs2, gcur2, x1, x_task, W3, b3, W4, b4, x2);
    pool_critic<<<1, 256, 0, stream>>>(x2, Wc1, bc1, Wc2, bc2, out);
}

// Round 6
// 242.626 us; speedup vs baseline: 3.7202x; 1.0890x over previous
//
#include <hip/hip_runtime.h>
#include <hip/hip_bf16.h>

// ---------------------------------------------------------------------------
// Round-6 structure:
//   bin_edges_all: 512 blocks; first 256 bin the goal->obs edges into 512
//     buckets of 128 obs rows, last 256 bin obs->task edges into 256 buckets
//     of 32 task rows (= one graph). Packed (row_in_bucket<<17 | src) writes
//     into per-bucket contiguous runs (1 global atomic per block-bucket).
//   gemm_all: xg1 = x_goal@W1 and obs = x_obs@W1 in one dispatch.
//   gather_mlp_obs: per bucket, register-cached counting sort (wave-0 shfl
//     scan, 2 barriers), per-row register gather, fused obs MLP with
//     FLOAT4 LDS matvec (16 b128 weight reads + 16 broadcast b128 h reads
//     per row instead of 128 scalar ds_read_b32 — round-5 was LDS-issue
//     bound at VALUBusy 44%).
//   gather_mlp_task_pool: per bucket (= 1 graph, 32 task rows), same sort,
//     8-chain gather from x1, fused W3 matvec + W4 dot + per-graph max/mean
//     pool + critic MLP -> out[graph]. No separate pool kernel.
// ---------------------------------------------------------------------------

#define CAP1 2816   // stage1: mean 2048/bucket, sigma~45  -> mean+17sigma
#define CAP2 5120   // stage2: mean 4096/bucket, sigma~64  -> mean+16sigma

// ------------------------- merged dense GEMM ------------------------------
// out[M,64] = X[M,128] @ W1[128,64]; blocks <1024 do x_goal, rest x_obs.
__global__ __launch_bounds__(256) void gemm_all(
    const float* __restrict__ x_goal, const float* __restrict__ x_obs,
    const float* __restrict__ W, float* __restrict__ xg1,
    float* __restrict__ obs)
{
    __shared__ float Ws[128 * 64];
    __shared__ float Xs[16 * 132];
    const int tid = threadIdx.x;
    const float* X;
    float* O;
    int row0;
    if (blockIdx.x < 1024) { X = x_goal; O = xg1; row0 = blockIdx.x * 16; }
    else                   { X = x_obs;  O = obs; row0 = (blockIdx.x - 1024) * 16; }
    for (int i = tid; i < 128 * 64 / 4; i += 256)
        ((float4*)Ws)[i] = ((const float4*)W)[i];
    for (int i = tid; i < 16 * 32; i += 256) {
        int r = i >> 5, c4 = i & 31;
        float4 v = ((const float4*)(X + (size_t)(row0 + r) * 128))[c4];
        *((float4*)(Xs + r * 132 + c4 * 4)) = v;
    }
    __syncthreads();
    const int rl = tid >> 4;
    const int cg = (tid & 15) * 4;
    float a0 = 0.f, a1 = 0.f, a2 = 0.f, a3 = 0.f;
    const float* xr = Xs + rl * 132;
    #pragma unroll 8
    for (int k = 0; k < 128; ++k) {
        float xv = xr[k];
        float4 wv = *((const float4*)(Ws + k * 64 + cg));
        a0 = fmaf(xv, wv.x, a0);
        a1 = fmaf(xv, wv.y, a1);
        a2 = fmaf(xv, wv.z, a2);
        a3 = fmaf(xv, wv.w, a3);
    }
    float4 o; o.x = a0; o.y = a1; o.z = a2; o.w = a3;
    *((float4*)(O + (size_t)(row0 + rl) * 64 + cg)) = o;
}

// ------------------- merged coarse binning --------------------------------
__global__ __launch_bounds__(256) void bin_edges_all(
    const int* __restrict__ go_src, const int* __restrict__ go_dst,
    const int* __restrict__ ot_src, const int* __restrict__ ot_dst,
    int* __restrict__ gcur1, int* __restrict__ gcur2,
    int* __restrict__ pairs1, int* __restrict__ pairs2, int nblk1)
{
    __shared__ int hist[512];
    __shared__ int cur[512];
    const int tid = threadIdx.x;
    const bool s1 = (int)blockIdx.x < nblk1;
    const int* src = s1 ? go_src : ot_src;
    const int* dst = s1 ? go_dst : ot_dst;
    int* gcur  = s1 ? gcur1 : gcur2;
    int* pairs = s1 ? pairs1 : pairs2;
    const int bsh  = s1 ? 7 : 5;
    const int rowm = s1 ? 127 : 31;
    const int nb   = s1 ? 512 : 256;
    const int cap  = s1 ? CAP1 : CAP2;
    const int blk  = s1 ? blockIdx.x : blockIdx.x - nblk1;

    for (int i = tid; i < nb; i += 256) hist[i] = 0;
    __syncthreads();
    const int base = blk * 4096;
    const int4* d4 = (const int4*)(dst + base);
    const int4* s4 = (const int4*)(src + base);
    int4 dv[4];
    #pragma unroll
    for (int k = 0; k < 4; ++k) {
        dv[k] = d4[k * 256 + tid];
        atomicAdd(&hist[dv[k].x >> bsh], 1);
        atomicAdd(&hist[dv[k].y >> bsh], 1);
        atomicAdd(&hist[dv[k].z >> bsh], 1);
        atomicAdd(&hist[dv[k].w >> bsh], 1);
    }
    __syncthreads();
    for (int i = tid; i < nb; i += 256)
        cur[i] = atomicAdd(&gcur[i], hist[i]);     // reserve contiguous run
    __syncthreads();
    #pragma unroll
    for (int k = 0; k < 4; ++k) {
        int4 sv = s4[k * 256 + tid];
        int d, s, b, p;
        d = dv[k].x; s = sv.x; b = d >> bsh; p = atomicAdd(&cur[b], 1);
        if (p < cap) pairs[(size_t)b * cap + p] = ((d & rowm) << 17) | s;
        d = dv[k].y; s = sv.y; b = d >> bsh; p = atomicAdd(&cur[b], 1);
        if (p < cap) pairs[(size_t)b * cap + p] = ((d & rowm) << 17) | s;
        d = dv[k].z; s = sv.z; b = d >> bsh; p = atomicAdd(&cur[b], 1);
        if (p < cap) pairs[(size_t)b * cap + p] = ((d & rowm) << 17) | s;
        d = dv[k].w; s = sv.w; b = d >> bsh; p = atomicAdd(&cur[b], 1);
        if (p < cap) pairs[(size_t)b * cap + p] = ((d & rowm) << 17) | s;
    }
}

// ------------- stage-1 gather + fused obs MLP -----------------------------
__global__ __launch_bounds__(1024) void gather_mlp_obs(
    const int* __restrict__ pairs, const int* __restrict__ cnt,
    const float* __restrict__ xg1, const float* __restrict__ obs,
    const float* __restrict__ b1, const float* __restrict__ W2,
    const float* __restrict__ b2, float* __restrict__ x1)
{
    constexpr int ROWS = 128;
    __shared__ int ssrc[CAP1];
    __shared__ int offs[ROWS + 1];
    __shared__ int rcnt[ROWS];
    __shared__ float W2t[64 * 68];       // transposed, stride 68 (16B aligned)
    __shared__ float hb[16 * 64];
    const int tid = threadIdx.x;
    const int b = blockIdx.x;

    // load + transpose W2: W2t[c][k] = W2[k][c]
    #pragma unroll
    for (int i = tid; i < 4096; i += 1024) {
        int k = i >> 6, c = i & 63;
        W2t[c * 68 + k] = W2[i];
    }
    if (tid < ROWS) rcnt[tid] = 0;
    __syncthreads();
    int n = cnt[b];
    if (n > CAP1) n = CAP1;
    const int* bp = pairs + (size_t)b * CAP1;

    // 1) histogram, caching packed edges in registers (<=3 per thread)
    int e0 = -1, e1 = -1, e2 = -1;
    {
        int i = tid;
        if (i < n) {
            e0 = bp[i]; atomicAdd(&rcnt[e0 >> 17], 1); i += 1024;
            if (i < n) {
                e1 = bp[i]; atomicAdd(&rcnt[e1 >> 17], 1); i += 1024;
                if (i < n) { e2 = bp[i]; atomicAdd(&rcnt[e2 >> 17], 1); }
            }
        }
    }
    __syncthreads();
    // 2) wave-0 shfl scan (2 elems/lane), rcnt becomes the scatter cursor
    if (tid < 64) {
        int v0 = rcnt[2 * tid], v1 = rcnt[2 * tid + 1];
        int s = v0 + v1;
        #pragma unroll
        for (int d = 1; d < 64; d <<= 1) {
            int t = __shfl_up(s, d);
            if (tid >= d) s += t;
        }
        int ex = s - v0 - v1;
        offs[2 * tid] = ex;
        offs[2 * tid + 1] = ex + v0;
        rcnt[2 * tid] = ex;
        rcnt[2 * tid + 1] = ex + v0;
        if (tid == 63) offs[ROWS] = s;
    }
    __syncthreads();
    // 3) scatter src ids into row-sorted order (register-cached edges)
    if (e0 >= 0) { int p = atomicAdd(&rcnt[e0 >> 17], 1); ssrc[p] = e0 & 0x1FFFF; }
    if (e1 >= 0) { int p = atomicAdd(&rcnt[e1 >> 17], 1); ssrc[p] = e1 & 0x1FFFF; }
    if (e2 >= 0) { int p = atomicAdd(&rcnt[e2 >> 17], 1); ssrc[p] = e2 & 0x1FFFF; }
    __syncthreads();
    // 4) per-row register gather + fused MLP (float4 LDS matvec)
    const int wv = tid >> 6;
    const int lane = tid & 63;
    const float bb1 = b1[lane];
    const float bb2 = b2[lane];
    float* hp = hb + wv * 64;
    const float4* h4 = (const float4*)hp;
    const float4* wrow = (const float4*)(W2t + lane * 68);
    for (int r = wv; r < ROWS; r += 16) {
        int beg = offs[r], end = offs[r + 1];
        float a0 = 0.f, a1 = 0.f, a2 = 0.f, a3 = 0.f;
        int e = beg;
        for (; e + 4 <= end; e += 4) {
            int s0 = ssrc[e], s1 = ssrc[e + 1], s2 = ssrc[e + 2], s3 = ssrc[e + 3];
            a0 += xg1[(size_t)s0 * 64 + lane];
            a1 += xg1[(size_t)s1 * 64 + lane];
            a2 += xg1[(size_t)s2 * 64 + lane];
            a3 += xg1[(size_t)s3 * 64 + lane];
        }
        for (; e < end; ++e)
            a0 += xg1[(size_t)ssrc[e] * 64 + lane];
        size_t gi = (((size_t)b * ROWS) + r) * 64 + lane;
        float acc = (a0 + a1) + (a2 + a3) + obs[gi];     // += x_obs@W1 base
        hp[lane] = fmaxf(acc + bb1, 0.f);                // same-wave stage
        float a = bb2;
        #pragma unroll 8
        for (int kc = 0; kc < 16; ++kc) {
            float4 hv = h4[kc];          // wave-uniform broadcast b128
            float4 wv4 = wrow[kc];       // per-lane b128
            a = fmaf(hv.x, wv4.x, a);
            a = fmaf(hv.y, wv4.y, a);
            a = fmaf(hv.z, wv4.z, a);
            a = fmaf(hv.w, wv4.w, a);
        }
        x1[gi] = fmaxf(a, 0.f);
    }
}

// ------------- stage-2 gather + fused task MLP + pool + critic ------------
// One 1024-thread WG per bucket of 32 task rows == one graph.
__global__ __launch_bounds__(1024) void gather_mlp_task_pool(
    const int* __restrict__ pairs, const int* __restrict__ cnt,
    const float* __restrict__ x1, const float* __restrict__ x_task,
    const float* __restrict__ W3, const float* __restrict__ b3,
    const float* __restrict__ W4, const float* __restrict__ b4,
    const float* __restrict__ Wc1, const float* __restrict__ bc1,
    const float* __restrict__ Wc2, const float* __restrict__ bc2,
    float* __restrict__ out)
{
    constexpr int ROWS = 32;
    __shared__ int ssrc[CAP2];
    __shared__ int offs[ROWS + 1];
    __shared__ int rcnt[ROWS];
    __shared__ float W3t[64 * 68];
    __shared__ float hb[16 * 64];
    __shared__ float xrow[ROWS];
    const int tid = threadIdx.x;
    const int b = blockIdx.x;

    #pragma unroll
    for (int i = tid; i < 4096; i += 1024) {
        int k = i >> 6, c = i & 63;
        W3t[c * 68 + k] = W3[i];
    }
    if (tid < ROWS) rcnt[tid] = 0;
    __syncthreads();
    int n = cnt[b];
    if (n > CAP2) n = CAP2;
    const int* bp = pairs + (size_t)b * CAP2;

    // 1) histogram with register-cached packed edges (<=5 per thread)
    int e0 = -1, e1 = -1, e2 = -1, e3 = -1, e4 = -1;
    {
        int i = tid;
        if (i < n) { e0 = bp[i]; atomicAdd(&rcnt[e0 >> 17], 1); i += 1024;
        if (i < n) { e1 = bp[i]; atomicAdd(&rcnt[e1 >> 17], 1); i += 1024;
        if (i < n) { e2 = bp[i]; atomicAdd(&rcnt[e2 >> 17], 1); i += 1024;
        if (i < n) { e3 = bp[i]; atomicAdd(&rcnt[e3 >> 17], 1); i += 1024;
        if (i < n) { e4 = bp[i]; atomicAdd(&rcnt[e4 >> 17], 1); } } } } }
    }
    __syncthreads();
    // 2) wave-0 shfl scan over 32 rows
    if (tid < 32) {
        int v = rcnt[tid];
        int s = v;
        #pragma unroll
        for (int d = 1; d < 32; d <<= 1) {
            int t = __shfl_up(s, d);
            if (tid >= d) s += t;
        }
        int ex = s - v;
        offs[tid] = ex;
        rcnt[tid] = ex;
        if (tid == 31) offs[ROWS] = s;
    }
    __syncthreads();
    // 3) scatter
    if (e0 >= 0) { int p = atomicAdd(&rcnt[e0 >> 17], 1); ssrc[p] = e0 & 0x1FFFF; }
    if (e1 >= 0) { int p = atomicAdd(&rcnt[e1 >> 17], 1); ssrc[p] = e1 & 0x1FFFF; }
    if (e2 >= 0) { int p = atomicAdd(&rcnt[e2 >> 17], 1); ssrc[p] = e2 & 0x1FFFF; }
    if (e3 >= 0) { int p = atomicAdd(&rcnt[e3 >> 17], 1); ssrc[p] = e3 & 0x1FFFF; }
    if (e4 >= 0) { int p = atomicAdd(&rcnt[e4 >> 17], 1); ssrc[p] = e4 & 0x1FFFF; }
    __syncthreads();

    // 4) two rows per wave: gather 8-chain + fused task MLP -> xrow[r]
    const int wv = tid >> 6;
    const int lane = tid & 63;
    const float bb3 = b3[lane];
    const float w4l = W4[lane];
    const float b4c = b4[0];
    float* hp = hb + wv * 64;
    const float4* h4 = (const float4*)hp;
    const float4* wrow = (const float4*)(W3t + lane * 68);
    #pragma unroll
    for (int half = 0; half < 2; ++half) {
        const int r = wv + half * 16;
        const int row = b * ROWS + r;
        int beg = offs[r], end = offs[r + 1];
        float a0 = 0.f, a1 = 0.f, a2 = 0.f, a3 = 0.f;
        float a4 = 0.f, a5 = 0.f, a6 = 0.f, a7 = 0.f;
        int e = beg;
        for (; e + 8 <= end; e += 8) {
            int s0 = ssrc[e],     s1 = ssrc[e + 1], s2 = ssrc[e + 2], s3 = ssrc[e + 3];
            int s4 = ssrc[e + 4], s5 = ssrc[e + 5], s6 = ssrc[e + 6], s7 = ssrc[e + 7];
            a0 += x1[(size_t)s0 * 64 + lane];
            a1 += x1[(size_t)s1 * 64 + lane];
            a2 += x1[(size_t)s2 * 64 + lane];
            a3 += x1[(size_t)s3 * 64 + lane];
            a4 += x1[(size_t)s4 * 64 + lane];
            a5 += x1[(size_t)s5 * 64 + lane];
            a6 += x1[(size_t)s6 * 64 + lane];
            a7 += x1[(size_t)s7 * 64 + lane];
        }
        for (; e < end; ++e)
            a0 += x1[(size_t)ssrc[e] * 64 + lane];
        float t = ((a0 + a1) + (a2 + a3)) + ((a4 + a5) + (a6 + a7))
                + x_task[(size_t)row * 64 + lane];
        hp[lane] = t;                            // same-wave stage (no relu)
        float a = bb3;
        #pragma unroll 8
        for (int kc = 0; kc < 16; ++kc) {
            float4 hv = h4[kc];
            float4 wv4 = wrow[kc];
            a = fmaf(hv.x, wv4.x, a);
            a = fmaf(hv.y, wv4.y, a);
            a = fmaf(hv.z, wv4.z, a);
            a = fmaf(hv.w, wv4.w, a);
        }
        float p = fmaxf(a, 0.f) * w4l;
        p += __shfl_xor(p, 1);
        p += __shfl_xor(p, 2);
        p += __shfl_xor(p, 4);
        p += __shfl_xor(p, 8);
        p += __shfl_xor(p, 16);
        p += __shfl_xor(p, 32);
        if (lane == 0) xrow[r] = p + b4c;
    }
    __syncthreads();
    // 5) pool + critic for this graph
    if (tid == 0) {
        float mx = -1e30f, sm = 0.f;
        #pragma unroll
        for (int i = 0; i < ROWS; ++i) {
            float v = xrow[i];
            mx = fmaxf(mx, v);
            sm += v;
        }
        float mn = sm * (1.f / 32.f);
        float o = bc2[0];
        #pragma unroll
        for (int j = 0; j < 8; ++j) {
            float t = fmaxf(mx * Wc1[j] + mn * Wc1[8 + j] + bc1[j], 0.f);
            o = fmaf(t, Wc2[j], o);
        }
        out[b] = o;
    }
}

extern "C" void kernel_launch(void* const* d_in, const int* in_sizes, int n_in,
                              void* d_out, int out_size, void* d_ws, size_t ws_size,
                              hipStream_t stream)
{
    const float* x_goal = (const float*)d_in[0];
    const float* x_obs  = (const float*)d_in[1];
    const float* x_task = (const float*)d_in[2];
    const int* go_src = (const int*)d_in[3];
    const int* go_dst = (const int*)d_in[4];
    const int* ot_src = (const int*)d_in[5];
    const int* ot_dst = (const int*)d_in[6];
    const float* W1  = (const float*)d_in[8];
    const float* b1  = (const float*)d_in[9];
    const float* W2  = (const float*)d_in[10];
    const float* b2  = (const float*)d_in[11];
    const float* W3  = (const float*)d_in[12];
    const float* b3  = (const float*)d_in[13];
    const float* W4  = (const float*)d_in[14];
    const float* b4  = (const float*)d_in[15];
    const float* Wc1 = (const float*)d_in[16];
    const float* bc1 = (const float*)d_in[17];
    const float* Wc2 = (const float*)d_in[18];
    const float* bc2 = (const float*)d_in[19];
    float* out = (float*)d_out;

    const int N_GOAL = 16384, N_OBS = 65536;
    const int E1 = in_sizes[3], E2 = in_sizes[5];
    const int NB1 = 512, NB2 = 256;

    // workspace (~47 MB of 256 MiB)
    char* w = (char*)d_ws;
    float* obs    = (float*)w;  w += (size_t)N_OBS * 64 * 4;        // 16 MB
    float* x1     = (float*)w;  w += (size_t)N_OBS * 64 * 4;        // 16 MB
    float* xg1    = (float*)w;  w += (size_t)N_GOAL * 64 * 4;       //  4 MB
    int*   pairs1 = (int*)w;    w += (size_t)NB1 * CAP1 * 4;        //  5.8 MB
    int*   pairs2 = (int*)w;    w += (size_t)NB2 * CAP2 * 4;        //  5.2 MB
    int*   gcur1  = (int*)w;    w += NB1 * 4;
    int*   gcur2  = (int*)w;    w += NB2 * 4;

    hipMemsetAsync(gcur1, 0, (NB1 + NB2) * 4, stream);

    const int nblk1 = E1 / 4096;
    bin_edges_all<<<nblk1 + E2 / 4096, 256, 0, stream>>>(
        go_src, go_dst, ot_src, ot_dst, gcur1, gcur2, pairs1, pairs2, nblk1);
    gemm_all<<<(N_GOAL + N_OBS) / 16, 256, 0, stream>>>(x_goal, x_obs, W1, xg1, obs);
    gather_mlp_obs<<<NB1, 1024, 0, stream>>>(pairs1, gcur1, xg1, obs, b1, W2, b2, x1);
    gather_mlp_task_pool<<<NB2, 1024, 0, stream>>>(pairs2, gcur2, x1, x_task,
                                                   W3, b3, W4, b4,
                                                   Wc1, bc1, Wc2, bc2, out);
}